// Round 1
// baseline (1747.051 us; speedup 1.0000x reference)
//
#include <hip/hip_runtime.h>
#include <hip/hip_bf16.h>

typedef __attribute__((ext_vector_type(4))) int i32x4;

// ---------------------------------------------------------------------------
// exact pow2 ceil: smallest power of two >= s  (s > 0, normal)
// replicates exp2(ceil(log2(s))) with mathematically-correct ceil
// ---------------------------------------------------------------------------
__device__ inline float pow2_ceil(float s) {
    unsigned u = __float_as_uint(s);
    if ((u & 0x007fffffu) == 0) return s;              // exact power of two
    return __uint_as_float(((u >> 23) + 1) << 23);     // bump exponent
}

// ---------------------------------------------------------------------------
// column absmax: grid (K/1024, rows/64), 256 thr; thread owns 4 consecutive
// cols via float4, loops 64 rows, one atomicMax-as-uint per col (vals >= 0)
// ---------------------------------------------------------------------------
__global__ __launch_bounds__(256) void colmax_kernel(
    const float* __restrict__ src, int K, float* __restrict__ out)
{
    int col = (blockIdx.x * 256 + threadIdx.x) * 4;
    const float* p = src + (size_t)blockIdx.y * 64 * K + col;
    float mx = 0.f, my = 0.f, mz = 0.f, mw = 0.f;
    for (int r = 0; r < 64; ++r) {
        float4 v = *(const float4*)p;
        mx = fmaxf(mx, fabsf(v.x));
        my = fmaxf(my, fabsf(v.y));
        mz = fmaxf(mz, fabsf(v.z));
        mw = fmaxf(mw, fabsf(v.w));
        p += K;
    }
    atomicMax((unsigned int*)(out + col + 0), __float_as_uint(mx));
    atomicMax((unsigned int*)(out + col + 1), __float_as_uint(my));
    atomicMax((unsigned int*)(out + col + 2), __float_as_uint(mz));
    atomicMax((unsigned int*)(out + col + 3), __float_as_uint(mw));
}

__global__ __launch_bounds__(256) void smooth_kernel(
    const float* __restrict__ xmax, const float* __restrict__ wmax,
    float* __restrict__ smooth, int K)
{
    int i = blockIdx.x * 256 + threadIdx.x;
    if (i < K) smooth[i] = sqrtf(xmax[i] * wmax[i]);
}

// ---------------------------------------------------------------------------
// per-row quant. One block (256 thr) per row, K=4096 -> 16 vals/thread kept
// in registers between the absmax pass and the quantize pass.
// MUL=false: v = x / smooth   (activation);  MUL=true: v = w * smooth (weight)
// ---------------------------------------------------------------------------
template <bool MUL>
__global__ __launch_bounds__(256) void quant_kernel(
    const float* __restrict__ src, const float* __restrict__ smooth,
    signed char* __restrict__ q, float* __restrict__ scale_out, int K)
{
    __shared__ float red[4];
    const int row = blockIdx.x;
    const int tid = threadIdx.x;
    const float* sr = src + (size_t)row * K;

    float v[16];
    float amax = 0.f;
#pragma unroll
    for (int c = 0; c < 4; ++c) {
        int idx = (c << 10) + (tid << 2);
        float4 xv = *(const float4*)(sr + idx);
        float4 sv = *(const float4*)(smooth + idx);
        float a, b, cc, d;
        if (MUL) { a = xv.x * sv.x; b = xv.y * sv.y; cc = xv.z * sv.z; d = xv.w * sv.w; }
        else     { a = xv.x / sv.x; b = xv.y / sv.y; cc = xv.z / sv.z; d = xv.w / sv.w; }
        v[c*4+0] = a; v[c*4+1] = b; v[c*4+2] = cc; v[c*4+3] = d;
        amax = fmaxf(amax, fmaxf(fmaxf(fabsf(a), fabsf(b)), fmaxf(fabsf(cc), fabsf(d))));
    }
    // block max reduce
#pragma unroll
    for (int off = 32; off > 0; off >>= 1)
        amax = fmaxf(amax, __shfl_down(amax, off, 64));
    if ((tid & 63) == 0) red[tid >> 6] = amax;
    __syncthreads();
    float m = fmaxf(fmaxf(red[0], red[1]), fmaxf(red[2], red[3]));

    float s = fmaxf(m / 127.0f, 1e-30f);
    float scale = pow2_ceil(s);
    if (tid == 0) scale_out[row] = scale;
    float inv = 1.0f / scale;   // scale is pow2 -> v*inv == v/scale exactly

#pragma unroll
    for (int c = 0; c < 4; ++c) {
        char4 o;
        o.x = (signed char)(int)fminf(fmaxf(rintf(v[c*4+0] * inv), -127.f), 127.f);
        o.y = (signed char)(int)fminf(fmaxf(rintf(v[c*4+1] * inv), -127.f), 127.f);
        o.z = (signed char)(int)fminf(fmaxf(rintf(v[c*4+2] * inv), -127.f), 127.f);
        o.w = (signed char)(int)fminf(fmaxf(rintf(v[c*4+3] * inv), -127.f), 127.f);
        *(char4*)(q + (size_t)row * K + (c << 10) + (tid << 2)) = o;
    }
}

// ---------------------------------------------------------------------------
// i8 GEMM, m97 structure: 128x128 tile, BK=64, 256 thr = 4 waves (each 64x64),
// global_load_lds width=16, mfma_i32_16x16x64_i8, fp32 scaled epilogue.
// A = x_q [M,K] row-major, B = w_q [N,K] row-major (NT GEMM, both K-contig).
// ---------------------------------------------------------------------------
__global__ __launch_bounds__(256) void gemm_i8_kernel(
    const signed char* __restrict__ Aq, const signed char* __restrict__ Bq,
    const float* __restrict__ xs, const float* __restrict__ wsc,
    const float* __restrict__ bias, float* __restrict__ out,
    int M, int N, int K)
{
    __shared__ signed char lA[128 * 64];   // 8 KB
    __shared__ signed char lB[128 * 64];   // 8 KB

    const int tid  = threadIdx.x;
    const int bn   = blockIdx.x, bm = blockIdx.y;
    const int lane = tid & 63;
    const int wave = tid >> 6;
    const int quad = lane >> 4, r16 = lane & 15;
    const int wm = (wave & 1) << 6;   // wave's 64-row slab
    const int wn = (wave >> 1) << 6;  // wave's 64-col slab

    i32x4 acc[4][4] = {};

    const signed char* Ab = Aq + (size_t)(bm * 128) * K;
    const signed char* Bb = Bq + (size_t)(bn * 128) * K;

    const int arow = tid >> 2;            // 0..63
    const int acb  = (tid & 3) << 4;      // 0/16/32/48 byte within BK

    for (int k0 = 0; k0 < K; k0 += 64) {
        __builtin_amdgcn_global_load_lds(
            (const __attribute__((address_space(1))) unsigned char*)(Ab + (size_t)arow * K + k0 + acb),
            (__attribute__((address_space(3))) unsigned char*)(lA + tid * 16), 16, 0, 0);
        __builtin_amdgcn_global_load_lds(
            (const __attribute__((address_space(1))) unsigned char*)(Ab + (size_t)(arow + 64) * K + k0 + acb),
            (__attribute__((address_space(3))) unsigned char*)(lA + 4096 + tid * 16), 16, 0, 0);
        __builtin_amdgcn_global_load_lds(
            (const __attribute__((address_space(1))) unsigned char*)(Bb + (size_t)arow * K + k0 + acb),
            (__attribute__((address_space(3))) unsigned char*)(lB + tid * 16), 16, 0, 0);
        __builtin_amdgcn_global_load_lds(
            (const __attribute__((address_space(1))) unsigned char*)(Bb + (size_t)(arow + 64) * K + k0 + acb),
            (__attribute__((address_space(3))) unsigned char*)(lB + 4096 + tid * 16), 16, 0, 0);
        __syncthreads();   // drains vmcnt before barrier

        i32x4 af[4], bf[4];
#pragma unroll
        for (int mi = 0; mi < 4; ++mi)
            af[mi] = *(const i32x4*)(lA + ((wm + mi * 16 + r16) << 6) + (quad << 4));
#pragma unroll
        for (int ni = 0; ni < 4; ++ni)
            bf[ni] = *(const i32x4*)(lB + ((wn + ni * 16 + r16) << 6) + (quad << 4));
#pragma unroll
        for (int mi = 0; mi < 4; ++mi)
#pragma unroll
            for (int ni = 0; ni < 4; ++ni)
                acc[mi][ni] = __builtin_amdgcn_mfma_i32_16x16x64_i8(af[mi], bf[ni], acc[mi][ni], 0, 0, 0);
        __syncthreads();
    }

    // epilogue: out = acc * x_scale[m] * w_scale[n] + bias[n]
#pragma unroll
    for (int ni = 0; ni < 4; ++ni) {
        int gn = bn * 128 + wn + ni * 16 + r16;
        float wv = wsc[gn];
        float bv = bias[gn];
#pragma unroll
        for (int mi = 0; mi < 4; ++mi) {
#pragma unroll
            for (int i = 0; i < 4; ++i) {
                int gm = bm * 128 + wm + mi * 16 + quad * 4 + i;
                out[(size_t)gm * N + gn] = (float)acc[mi][ni][i] * xs[gm] * wv + bv;
            }
        }
    }
}

// ---------------------------------------------------------------------------
extern "C" void kernel_launch(void* const* d_in, const int* in_sizes, int n_in,
                              void* d_out, int out_size, void* d_ws, size_t ws_size,
                              hipStream_t stream)
{
    const float* x    = (const float*)d_in[0];
    const float* w    = (const float*)d_in[1];
    const float* bias = (const float*)d_in[2];
    float* out = (float*)d_out;

    const int N = in_sizes[2];
    const int K = in_sizes[1] / N;
    const int M = in_sizes[0] / K;

    // workspace layout
    float* xmax   = (float*)d_ws;                 // K
    float* wmax   = xmax + K;                     // K
    float* smooth = wmax + K;                     // K
    float* xscale = smooth + K;                   // M
    float* wscale = xscale + M;                   // N
    signed char* xq = (signed char*)(wscale + N); // M*K
    signed char* wq = xq + (size_t)M * K;         // N*K

    hipMemsetAsync(xmax, 0, (size_t)2 * K * sizeof(float), stream);

    colmax_kernel<<<dim3(K / 1024, M / 64), 256, 0, stream>>>(x, K, xmax);
    colmax_kernel<<<dim3(K / 1024, N / 64), 256, 0, stream>>>(w, K, wmax);
    smooth_kernel<<<dim3((K + 255) / 256), 256, 0, stream>>>(xmax, wmax, smooth, K);
    quant_kernel<false><<<dim3(M), 256, 0, stream>>>(x, smooth, xq, xscale, K);
    quant_kernel<true ><<<dim3(N), 256, 0, stream>>>(w, smooth, wq, wscale, K);
    gemm_i8_kernel<<<dim3(N / 128, M / 128), 256, 0, stream>>>(
        xq, wq, xscale, wscale, bias, out, M, N, K);
}